// Round 7
// baseline (829.877 us; speedup 1.0000x reference)
//
#include <hip/hip_runtime.h>
#include <hip/hip_bf16.h>

typedef __hip_bfloat16 BF;
typedef __bf16 v8bf __attribute__((ext_vector_type(8)));
typedef float v4f __attribute__((ext_vector_type(4)));

constexpr int SEQ = 2048;
constexpr int DIMC = 512;
constexpr int BSZ = 8;

// flags
#define GF_RELU 1
#define GF_CAUSAL 2   // mask col>row with 0, skip tiles entirely above diagonal
#define GF_KCAP 4     // limit K-loop to diagonal cap (h GEMM); also reverses by-order
#define GF_QKV 8      // route columns: 0-511->outB(q), 512-1023->outF-as-BF(k), 1024-1535->outV(v)
#define GF_BATCH8 16  // 1D grid, batch z = id&7 (XCD-pinned batches)
#define GF_HSTAT 32   // fp32 epilogue also accumulates per-column sum/sumsq into hsum/hsq
#define GF_SIMPLE 64  // decode: by = id % nbx, bx = id / nbx (small grids)
#define GF_PAIR 128   // each block does 2 adjacent n-tiles (grid-tail elimination)

// s_waitcnt immediates (gfx9: vmcnt[3:0]+[15:14], expcnt[6:4]=7 nowait, lgkmcnt[11:8]=0xF nowait)
#define WAIT_VM4 0x0F74
#define WAIT_VM0 0x0F70

__device__ __forceinline__ void async16(BF* lds, const BF* g) {
  __builtin_amdgcn_global_load_lds(
      (const __attribute__((address_space(1))) void*)g,
      (__attribute__((address_space(3))) void*)lds,
      16, 0, 0);
}

// C[M,N] = A[M,K] @ W[N,K]^T (both K-contiguous), bf16 in, fp32 accum.
// Proven structure: 128x128 tile, BK=32, dbuf LDS 32 KB, prefetch dist-1,
// vmcnt(4)-gated barriers, XOR swizzle, 4 blocks/CU.
// Ledger: R1 256^2/8-phase regressed (grid tails, shallow K). R4 256x128 at
// 6 waves/EU SPILLED (unified VGPR; 64x64/wave job ~120 regs -> max 4
// waves/EU; slots pinned at 1024). R4 LDS-coalesced bf16 stores: -77 us.
// R5 GF_HSTAT fused stats: ~neutral (epilogue cost ate the re-read win).
// R6: GF_PAIR — qkv grid 1536 was 1.5 rounds on 1024 slots; 768 blocks x
// 2 sequential n-tiles = one full round. K-loop untouched.
__global__ __launch_bounds__(256, 4) void gemm_bt(
    const BF* __restrict__ A, const BF* __restrict__ W, const float* __restrict__ bias,
    BF* __restrict__ outB, float* __restrict__ outF, BF* __restrict__ outV,
    float* __restrict__ hsum, float* __restrict__ hsq,
    int M, int N, int K, int nbx,
    long long strideA, long long strideW, long long strideC,
    float scale, int flags)
{
  const int id = blockIdx.x;
  int z, bx, by;
  if (flags & GF_BATCH8) {
    z = id & 7;
    const int t = id >> 3;
    bx = t % nbx;
    by = t / nbx;
    if (flags & GF_KCAP) by = (M >> 7) - 1 - by;  // long-K tiles first
  } else if (flags & GF_SIMPLE) {
    z = 0;
    by = id % nbx;   // nbx = m-tile count here
    bx = id / nbx;
  } else {
    z = 0;
    by = (id & 7) + ((id >> 3) & 15) * 8;  // m-panel, XCD-pinned (128 panels)
    bx = id >> 7;                          // n-tile (or n-pair if GF_PAIR)
  }
  const int m0 = by * 128;
  if ((flags & GF_CAUSAL) && bx * 128 > m0) return;  // tile fully above diagonal

  const BF* __restrict__ Ab = A + (size_t)z * strideA;
  const BF* __restrict__ Wb = W + (size_t)z * strideW;
  const size_t coff = (size_t)z * strideC;

  const int tid = threadIdx.x;
  const int w = tid >> 6;
  const int lane = tid & 63;
  const int lane15 = lane & 15;
  const int quad = lane >> 4;
  const int wr = w >> 1, wc = w & 1;
  const int rl = lane >> 2;
  const int clsw = ((lane & 3) ^ ((rl >> 1) & 3)) << 3;  // swizzled k-offset in elements

  // 32 KB merged: K-loop view sA/sW dbuf; epilogue view: bf16 tile OR stats scratch.
  __shared__ __align__(16) BF smem[16384];
  BF* sA = smem;
  BF* sW = smem + 8192;

  int Klim = K;
  if (flags & GF_KCAP) { int kc = m0 + 128; if (kc < Klim) Klim = kc; }
  const int ksteps = Klim >> 5;
  const int nrep = (flags & GF_PAIR) ? 2 : 1;

  for (int rp = 0; rp < nrep; ++rp) {
    const int n0 = (flags & GF_PAIR) ? (bx * 2 + rp) * 128 : bx * 128;
    if (rp) __syncthreads();  // prior epilogue's smem reads done before re-staging

    v4f acc[4][4];
    {
      v4f zero = {0.f, 0.f, 0.f, 0.f};
#pragma unroll
      for (int a = 0; a < 4; ++a)
#pragma unroll
        for (int b = 0; b < 4; ++b) acc[a][b] = zero;
    }

    auto stage = [&](int kk, int buf) {
      const int k0 = kk << 5;
#pragma unroll
      for (int i = 0; i < 2; ++i) {
        const int r0 = w * 32 + i * 16;  // wave-uniform 16-row chunk
        async16(&sA[buf * 4096 + r0 * 32], Ab + (size_t)(m0 + r0 + rl) * K + (k0 + clsw));
        async16(&sW[buf * 4096 + r0 * 32], Wb + (size_t)(n0 + r0 + rl) * K + (k0 + clsw));
      }
    };

    stage(0, 0);
    const int sw = quad ^ ((lane15 >> 1) & 3);  // read-side swizzle

    for (int kk = 0; kk < ksteps; ++kk) {
      const int cur = kk & 1;
      if (kk + 1 < ksteps) {
        stage(kk + 1, cur ^ 1);                 // prefetch stays in flight across the barrier
        __builtin_amdgcn_s_waitcnt(WAIT_VM4);   // retire only this iter's 4 loads
      } else {
        __builtin_amdgcn_s_waitcnt(WAIT_VM0);
      }
      __builtin_amdgcn_s_barrier();             // buf[cur] fully populated by all waves

      v8bf aF[4], wF[4];
      const v8bf* sAv = (const v8bf*)(sA + cur * 4096);
      const v8bf* sWv = (const v8bf*)(sW + cur * 4096);
#pragma unroll
      for (int t = 0; t < 4; ++t) {
        aF[t] = sAv[(wr * 64 + t * 16 + lane15) * 4 + sw];
        wF[t] = sWv[(wc * 64 + t * 16 + lane15) * 4 + sw];
      }
#pragma unroll
      for (int mt = 0; mt < 4; ++mt)
#pragma unroll
        for (int nt = 0; nt < 4; ++nt)
          acc[mt][nt] = __builtin_amdgcn_mfma_f32_16x16x32_bf16(aF[mt], wF[nt], acc[mt][nt], 0, 0, 0);
      __builtin_amdgcn_s_barrier();             // all waves consumed buf[cur]
    }

    // ---- epilogue ----
    // C/D layout col=lane&15, row=quad*4+i
    if ((flags & GF_QKV) || (outB && !outF)) {
      // bf16 path: stage tile in LDS (chunk-XOR swizzle), then 8 coalesced
      // 16B stores per thread.
#pragma unroll
      for (int mt = 0; mt < 4; ++mt) {
#pragma unroll
        for (int nt = 0; nt < 4; ++nt) {
          const int col = wc * 64 + nt * 16 + lane15;
          const int cg = n0 + col;
          const float bv = bias ? bias[cg] : 0.0f;
#pragma unroll
          for (int i = 0; i < 4; ++i) {
            const int row = wr * 64 + mt * 16 + quad * 4 + i;
            float v = acc[mt][nt][i] * scale + bv;
            if ((flags & GF_RELU) && v < 0.f) v = 0.f;
            if ((flags & GF_CAUSAL) && cg > m0 + row) v = 0.f;
            smem[row * 128 + ((((col >> 3) ^ ((row >> 2) & 3)) << 3) | (col & 7))] =
                __float2bfloat16(v);
          }
        }
      }
      __syncthreads();
      BF* dst;
      int ldc, coloff;
      if (flags & GF_QKV) {
        const int seg = n0 >> 9;  // 128-col tile lies wholly in q, k, or v
        dst = (seg == 0) ? outB : (seg == 1 ? (BF*)outF : outV);
        ldc = 512;
        coloff = n0 & 511;
      } else {
        dst = outB + coff;
        ldc = N;
        coloff = n0;
      }
#pragma unroll
      for (int p = 0; p < 8; ++p) {
        const int g = p * 256 + tid;
        const int row = g >> 4, ch = g & 15;
        const v8bf val = *(const v8bf*)(smem + row * 128 + ((ch ^ ((row >> 2) & 3)) << 3));
        *(v8bf*)(dst + (size_t)(m0 + row) * ldc + coloff + ch * 8) = val;
      }
    } else {
      // fp32 path (h32): scalar stores + optional fused column stats
      float psum[4] = {0.f, 0.f, 0.f, 0.f};
      float psq[4] = {0.f, 0.f, 0.f, 0.f};
#pragma unroll
      for (int mt = 0; mt < 4; ++mt) {
        const int rb = m0 + wr * 64 + mt * 16 + quad * 4;
#pragma unroll
        for (int nt = 0; nt < 4; ++nt) {
          const int cg = n0 + wc * 64 + nt * 16 + lane15;
          const float bv = bias ? bias[cg] : 0.0f;
#pragma unroll
          for (int i = 0; i < 4; ++i) {
            const int rg = rb + i;
            float v = acc[mt][nt][i] * scale + bv;
            if ((flags & GF_RELU) && v < 0.f) v = 0.f;
            if ((flags & GF_CAUSAL) && cg > rg) v = 0.f;
            if (outB) outB[coff + (size_t)rg * N + cg] = __float2bfloat16(v);
            if (outF) outF[coff + (size_t)rg * N + cg] = v;
            psum[nt] += v;
            psq[nt] += v * v;
          }
        }
      }
      if (flags & GF_HSTAT) {
        // per-column reduce: col = wc*64+nt*16+lane15 (0..127),
        // contributor = wr*4+quad (0..7). 8 KB scratch in smem.
        float* fs = (float*)smem;
        __syncthreads();  // K-loop reads of smem are done
#pragma unroll
        for (int nt = 0; nt < 4; ++nt) {
          const int col = wc * 64 + nt * 16 + lane15;
          const int cont = wr * 4 + quad;
          fs[col * 8 + cont] = psum[nt];
          fs[1024 + col * 8 + cont] = psq[nt];
        }
        __syncthreads();
        if (tid < 128) {
          float s = 0.f, q = 0.f;
#pragma unroll
          for (int c = 0; c < 8; ++c) { s += fs[tid * 8 + c]; q += fs[1024 + tid * 8 + c]; }
          atomicAdd(hsum + z * 512 + n0 + tid, s);
          atomicAdd(hsq + z * 512 + n0 + tid, q);
        }
      }
    }
  }
}

// x[b,s,:] = concat(emb_table[idx[b,s]][0:448], feats[b,s,0:64]) -> bf16
__global__ void gather_kernel(const int* __restrict__ seq, const float* __restrict__ feats,
                              const float* __restrict__ emb, BF* __restrict__ xb) {
  const int row = blockIdx.x;  // b*SEQ + s
  const int t = threadIdx.x;
  const int idx = seq[row];
  BF* xr = xb + (size_t)row * DIMC;
  if (t < 224) {
    const float2 e = *(const float2*)(emb + (size_t)idx * 448 + t * 2);
    xr[t * 2] = __float2bfloat16(e.x);
    xr[t * 2 + 1] = __float2bfloat16(e.y);
  } else {
    const int j = (t - 224) * 2;
    const float2 f = *(const float2*)(feats + (size_t)row * 64 + j);
    xr[448 + j] = __float2bfloat16(f.x);
    xr[448 + j + 1] = __float2bfloat16(f.y);
  }
}

// one-shot weight prep: wb = bf16(W1|W2), wqkv = bf16 packed [2][1536][512],
// bqkv packed bias, hstat zeroed. R6: also w2t = bf16(W2[0]^T) for the
// Wf = Wqkv1 @ W2_0 fusion GEMM. Grid 2816x256.
__global__ void prep_kernel(const float* __restrict__ W1, const float* __restrict__ W2,
                            const float* __restrict__ Wq, const float* __restrict__ Wk,
                            const float* __restrict__ Wv, const float* __restrict__ bq,
                            const float* __restrict__ bk, const float* __restrict__ bv,
                            BF* __restrict__ wb, BF* __restrict__ wqkv, float* __restrict__ bqkv,
                            float* __restrict__ hstat, BF* __restrict__ w2t) {
  const int t = blockIdx.x * 256 + threadIdx.x;
  if (t >= 655360) {  // w2t: 262144 elems, 65536 threads
    const int j = (t - 655360) * 4;
    if (j < 262144) {
      const int c = j >> 9, k = j & 511;
#pragma unroll
      for (int e = 0; e < 4; ++e)
        w2t[(size_t)c * 512 + k + e] = __float2bfloat16(W2[(size_t)(k + e) * 512 + c]);
    }
    return;
  }
  const long long i = (long long)t * 4;
  if (t < 4096) {  // zero hstat: 16384 floats
    float4 zz = {0.f, 0.f, 0.f, 0.f};
    *(float4*)(hstat + t * 4) = zz;
  }
  float4 v;
  BF* o;
  if (i < 1048576) {  // wb: W1 | W2 (each 524,288)
    v = (i < 524288) ? *(const float4*)(W1 + i) : *(const float4*)(W2 + (i - 524288));
    o = wb + i;
  } else {            // wqkv: [l][q|k|v row][col]
    const long long j = i - 1048576;
    const int l = j >= 786432 ? 1 : 0;
    const long long rem = j - (long long)l * 786432;
    const int r = (int)(rem >> 9), c = (int)(rem & 511);
    const float* s = (r < 512) ? Wq : (r < 1024 ? Wk : Wv);
    v = *(const float4*)(s + (size_t)l * 262144 + (size_t)(r & 511) * 512 + c);
    o = wqkv + j;
  }
  o[0] = __float2bfloat16(v.x); o[1] = __float2bfloat16(v.y);
  o[2] = __float2bfloat16(v.z); o[3] = __float2bfloat16(v.w);
  if (t < 768) {  // bqkv: 3072 elems
#pragma unroll
    for (int e = t * 4; e < t * 4 + 4; ++e) {
      const int l = e / 1536, r = e % 1536;
      const float* s = (r < 512) ? bq : (r < 1024 ? bk : bv);
      bqkv[e] = s[l * 512 + (r & 511)];
    }
  }
}

// R6: fused qkv-l1 bias: bfq[o] = bqkv1[o] + dot(Wqkv1[o,:], b2_l0)
__global__ void qkvbias_kernel(const BF* __restrict__ wq1, const float* __restrict__ bqkv1,
                               const float* __restrict__ b2l0, float* __restrict__ bfq) {
  const int o = blockIdx.x * 64 + (threadIdx.x >> 2);  // 24 blocks -> 1536 outputs
  const int seg = threadIdx.x & 3;
  const BF* wr = wq1 + (size_t)o * 512 + seg * 128;
  const float* bs = b2l0 + seg * 128;
  float acc = 0.f;
#pragma unroll
  for (int j = 0; j < 128; j += 8) {
    const v8bf wv = *(const v8bf*)(wr + j);
#pragma unroll
    for (int e = 0; e < 8; ++e) acc += bs[j + e] * (float)wv[e];
  }
  acc += __shfl_xor(acc, 1, 64);
  acc += __shfl_xor(acc, 2, 64);
  if (seg == 0) bfq[o] = bqkv1[o] + acc;
}

// vtmp [b][s][512] bf16 -> vt [b][512][s] bf16, 64x64 LDS tiles
__global__ void transpose_kernel(const BF* __restrict__ in, BF* __restrict__ out) {
  __shared__ BF t[64][65];
  const int b = blockIdx.z;
  const int s0 = blockIdx.x * 64, d0 = blockIdx.y * 64;
  const int dx = threadIdx.x & 63, ry = threadIdx.x >> 6;  // ry in 0..3
  const BF* ib = in + ((size_t)b * SEQ + s0) * DIMC + d0;
  BF* ob = out + ((size_t)b * DIMC + d0) * SEQ + s0;
#pragma unroll
  for (int i = 0; i < 16; ++i)
    t[ry + i * 4][dx] = ib[(size_t)(ry + i * 4) * DIMC + dx];
  __syncthreads();
#pragma unroll
  for (int i = 0; i < 16; ++i)
    ob[(size_t)(ry + i * 4) * SEQ + dx] = t[dx][ry + i * 4];
}

// stats from fused accumulators: mean/rstd per (b, d)
__global__ void seqstat_kernel(const float* __restrict__ hsum, const float* __restrict__ hsq,
                               float2* __restrict__ stat) {
  const int i = blockIdx.x * 256 + threadIdx.x;  // 4096 = 8*512
  const float s = hsum[i], q = hsq[i];
  const float mean = s / SEQ;
  float var = (q - mean * s) / (SEQ - 1);
  if (var < 0.f) var = 0.f;
  stat[i] = make_float2(mean, 1.0f / (sqrtf(var) + 2e-5f));
}

__global__ void seqapply_kernel(const float* __restrict__ h, const float2* __restrict__ stat,
                                BF* __restrict__ out) {
  const size_t i = ((size_t)blockIdx.x * 256 + threadIdx.x) * 4;  // 16,777,216 elems
  const int b = (int)(i >> 20);                                   // SEQ*DIMC = 2^20
  const int d = (int)(i & 511);
  const float4 v = *(const float4*)(h + i);
  const float2* sb = stat + (b << 9) + d;
  const float4 s01 = *(const float4*)(sb);
  const float4 s23 = *(const float4*)(sb + 2);
  out[i]     = __float2bfloat16((v.x - s01.x) * s01.y);
  out[i + 1] = __float2bfloat16((v.y - s01.z) * s01.w);
  out[i + 2] = __float2bfloat16((v.z - s23.x) * s23.y);
  out[i + 3] = __float2bfloat16((v.w - s23.z) * s23.w);
}

// R2 tail: last-row-only layer-1 ffn, 64 blocks/kernel.
__global__ void ffn1last_kernel(const float* __restrict__ h32, const float2* __restrict__ stat,
                                const BF* __restrict__ W1B, const float* __restrict__ b1,
                                float* __restrict__ f1g) {
  const int b = blockIdx.x >> 3, nb = blockIdx.x & 7;  // 64 blocks
  const int t = threadIdx.x;
  __shared__ float hn[512];
  const float* hr = h32 + ((size_t)b * SEQ + (SEQ - 1)) * DIMC;
  const float2* sb = stat + b * 512;
  for (int d = t; d < 512; d += 256) {
    const float2 s = sb[d];
    hn[d] = (hr[d] - s.x) * s.y;
  }
  __syncthreads();
  const int o = nb * 64 + (t >> 2);   // output column
  const int seg = t & 3;              // k-segment of 128
  const BF* wr = W1B + (size_t)o * 512 + seg * 128;
  const float* hs = hn + seg * 128;
  float acc = 0.f;
#pragma unroll
  for (int j = 0; j < 128; j += 8) {
    const v8bf wv = *(const v8bf*)(wr + j);
#pragma unroll
    for (int e = 0; e < 8; ++e) acc += hs[j + e] * (float)wv[e];
  }
  acc += __shfl_xor(acc, 1, 64);
  acc += __shfl_xor(acc, 2, 64);
  if (seg == 0) {
    const float v = acc + b1[o];
    f1g[b * 512 + o] = v > 0.f ? v : 0.f;
  }
}

__global__ void ffn2last_kernel(const float* __restrict__ f1g, const BF* __restrict__ W2B,
                                const float* __restrict__ b2, float* __restrict__ out) {
  const int b = blockIdx.x >> 3, nb = blockIdx.x & 7;  // 64 blocks
  const int t = threadIdx.x;
  __shared__ float f1[512];
  const float* fr = f1g + b * 512;
  for (int d = t; d < 512; d += 256) f1[d] = fr[d];
  __syncthreads();
  const int o = nb * 64 + (t >> 2);
  const int seg = t & 3;
  const BF* wr = W2B + (size_t)o * 512 + seg * 128;
  const float* fs = f1 + seg * 128;
  float acc = 0.f;
#pragma unroll
  for (int j = 0; j < 128; j += 8) {
    const v8bf wv = *(const v8bf*)(wr + j);
#pragma unroll
    for (int e = 0; e < 8; ++e) acc += fs[j + e] * (float)wv[e];
  }
  acc += __shfl_xor(acc, 1, 64);
  acc += __shfl_xor(acc, 2, 64);
  if (seg == 0) out[b * 512 + o] = acc + b2[o];
}

extern "C" void kernel_launch(void* const* d_in, const int* in_sizes, int n_in,
                              void* d_out, int out_size, void* d_ws, size_t ws_size,
                              hipStream_t stream) {
  const int* seq = (const int*)d_in[0];
  const float* feats = (const float*)d_in[1];
  const float* emb = (const float*)d_in[2];
  const float* Wq = (const float*)d_in[3];
  const float* bq = (const float*)d_in[4];
  const float* Wk = (const float*)d_in[5];
  const float* bk = (const float*)d_in[6];
  const float* Wv = (const float*)d_in[7];
  const float* bv = (const float*)d_in[8];
  const float* W1 = (const float*)d_in[9];
  const float* b1 = (const float*)d_in[10];
  const float* W2 = (const float*)d_in[11];
  const float* b2 = (const float*)d_in[12];
  float* out = (float*)d_out;

  char* ws = (char*)d_ws;
  const size_t MB = 1024 * 1024;
  BF* xb = (BF*)(ws);                   // 16 MB: x bf16; layer-1: k dest
  BF* qb = (BF*)(ws + 16 * MB);         // 16 MB: q bf16 (also hn l0)
  BF* kb = (BF*)(ws + 32 * MB);         // 16 MB: k bf16 l0 (then f1 l0 = qkv-l1 input)
  BF* vt = (BF*)(ws + 48 * MB);         // 16 MB: v^T bf16 [b][d][s]
  float* h32 = (float*)(ws + 64 * MB);  // 32 MB: attention out fp32
  BF* vtmp = (BF*)(ws + 64 * MB);       // overlays h32 head: v [b][s][d] before transpose
  BF* sc = (BF*)(ws + 96 * MB);         // 64 MB: scores bf16 [b][s][n]
  BF* wb = (BF*)(ws + 160 * MB);        // 2 MB: bf16 W1,W2
  BF* wqkv = (BF*)(ws + 162 * MB);      // 3 MB: bf16 packed qkv weights [2][1536][512]
  float* bqkv = (float*)(ws + 166 * MB);// 12 KB: packed qkv bias [2][1536]
  float* f1g = (float*)(ws + 166 * MB + 512 * 1024);  // 16 KB: last-row f1 fp32 [8][512]
  float* hstat = (float*)(ws + 167 * MB);// 64 KB: fused stats [2 layers][sum|sq][8][512]
  float2* stat = (float2*)(ws + 168 * MB); // 32 KB: seqnorm mean/rstd [8][512]
  BF* w2t = (BF*)(ws + 169 * MB);       // 0.5 MB: bf16 W2_l0^T [512][512]
  BF* wf = (BF*)(ws + 170 * MB);        // 1.5 MB: fused Wqkv1@W2_0 bf16 [1536][512]
  float* bfq = (float*)(ws + 172 * MB); // 6 KB: fused qkv-l1 bias fp32 [1536]

  const int WT = 2 * 512 * 512;
  prep_kernel<<<2816, 256, 0, stream>>>(W1, W2, Wq, Wk, Wv, bq, bk, bv, wb, wqkv, bqkv,
                                        hstat, w2t);
  // R6 fusion pre-pass: Wf = Wqkv1 @ W2_0 (bf16), bfq = bqkv1 + Wqkv1 @ b2_0
  qkvbias_kernel<<<24, 256, 0, stream>>>(wqkv + 786432, bqkv + 1536, b2, bfq);
  gemm_bt<<<48, 256, 0, stream>>>(wqkv + 786432, w2t, nullptr, wf, nullptr, nullptr,
      nullptr, nullptr, 1536, 512, 512, 12, 0, 0, 0, 1.0f, GF_SIMPLE);
  gather_kernel<<<BSZ * SEQ, 256, 0, stream>>>(seq, feats, emb, xb);

  const float attn_scale = 0.04419417382415922f;  // 1/sqrt(512)
  const dim3 blk(256);

  for (int l = 0; l < 2; ++l) {
    const BF* W1B = wb + (size_t)l * 262144;
    const BF* W2B = wb + (size_t)WT + (size_t)l * 262144;
    float* hsum_l = hstat + (size_t)l * 8192;
    float* hsq_l = hsum_l + 4096;
    // layer-1 k lives in xb (kb holds the fused-GEMM input f1)
    BF* kdst = (l == 0) ? kb : xb;

    // fused q|k|v projection: M=16384, N=1536, K=512 — GF_PAIR: 768 blocks,
    // 2 n-tiles each = one full round on 1024 slots.
    if (l == 0) {
      gemm_bt<<<768, blk, 0, stream>>>(xb, wqkv, bqkv, qb, (float*)kb, vtmp,
          nullptr, nullptr, 16384, 1536, 512, 0, 0, 0, 0, 1.0f, GF_QKV | GF_PAIR);
    } else {
      // R6: ffn2-l0 folded in — qkv1 = f1 @ Wf^T + bfq (exact linear algebra)
      gemm_bt<<<768, blk, 0, stream>>>(kb, wf, bfq, qb, (float*)xb, vtmp,
          nullptr, nullptr, 16384, 1536, 512, 0, 0, 0, 0, 1.0f, GF_QKV | GF_PAIR);
    }
    // coalesced v transpose -> vt [b][d][s]
    transpose_kernel<<<dim3(32, 8, 8), blk, 0, stream>>>(vtmp, vt);
    // scores = tril(q @ k^T) * scale (batch = id&7, XCD-pinned)
    gemm_bt<<<2048, blk, 0, stream>>>(qb, kdst, nullptr, sc, nullptr, nullptr,
        nullptr, nullptr, 2048, 2048, 512, 16,
        (long long)SEQ * DIMC, (long long)SEQ * DIMC, (long long)SEQ * SEQ,
        attn_scale, GF_CAUSAL | GF_BATCH8);
    // h = scores @ v (batch = id&7, K capped at diagonal; long-K first) + fused stats
    gemm_bt<<<512, blk, 0, stream>>>(sc, vt, nullptr, nullptr, h32, nullptr,
        hsum_l, hsq_l, 2048, 512, 2048, 4,
        (long long)SEQ * SEQ, (long long)DIMC * SEQ, (long long)SEQ * DIMC,
        1.0f, GF_KCAP | GF_BATCH8 | GF_HSTAT);
    // stats -> mean/rstd
    seqstat_kernel<<<16, 256, 0, stream>>>(hsum_l, hsq_l, stat);

    if (l == 0) {
      // normalize + ffn1 only (ffn2 folded into layer-1 qkv)
      seqapply_kernel<<<16384, 256, 0, stream>>>(h32, stat, qb);
      gemm_bt<<<512, blk, 0, stream>>>(qb, W1B, b1 + l * 512, kb, nullptr, nullptr,
          nullptr, nullptr, 16384, 512, 512, 4, 0, 0, 0, 1.0f, GF_RELU);
    } else {
      // layer-1: only the last row survives to the output — parallel fused tail
      ffn1last_kernel<<<64, blk, 0, stream>>>(h32, stat, W1B, b1 + 512, f1g);
      ffn2last_kernel<<<64, blk, 0, stream>>>(f1g, W2B, b2 + 512, out);
    }
  }
}

// Round 9
// 432.508 us; speedup vs baseline: 1.9188x; 1.9188x over previous
//
#include <hip/hip_runtime.h>
#include <hip/hip_bf16.h>

typedef __hip_bfloat16 BF;
typedef __bf16 v8bf __attribute__((ext_vector_type(8)));
typedef float v4f __attribute__((ext_vector_type(4)));

constexpr int SEQ = 2048;
constexpr int DIMC = 512;
constexpr int BSZ = 8;

// flags
#define GF_RELU 1
#define GF_CAUSAL 2   // mask col>row with 0, skip tiles entirely above diagonal
#define GF_KCAP 4     // limit K-loop to diagonal cap (h GEMM); also reverses by-order
#define GF_QKV 8      // route columns: 0-511->outB(q), 512-1023->outF-as-BF(k), 1024-1535->outV(v)
#define GF_BATCH8 16  // 1D grid, batch z = id&7 (XCD-pinned batches)
#define GF_HSTAT 32   // fp32 epilogue also writes per-block column sum/sumsq partials

// s_waitcnt immediates (gfx9: vmcnt[3:0]+[15:14], expcnt[6:4]=7 nowait, lgkmcnt[11:8]=0xF nowait)
#define WAIT_VM4 0x0F74
#define WAIT_VM0 0x0F70

__device__ __forceinline__ void async16(BF* lds, const BF* g) {
  __builtin_amdgcn_global_load_lds(
      (const __attribute__((address_space(1))) void*)g,
      (__attribute__((address_space(3))) void*)lds,
      16, 0, 0);
}

// C[M,N] = A[M,K] @ W[N,K]^T (both K-contiguous), bf16 in, fp32 accum.
// Proven structure: 128x128 tile, BK=32, dbuf LDS 32 KB, prefetch dist-1,
// vmcnt(4)-gated barriers, XOR swizzle, 4 blocks/CU.
// Ledger: R1 256^2/8-phase regressed (grid tails, shallow K). R4 256x128 at
// 6 waves/EU SPILLED (unified VGPR; 64x64/wave job ~120 regs -> max 4
// waves/EU; slots pinned at 1024). R4 LDS-coalesced bf16 stores: -77 us.
// R7 GF_PAIR rp-loop: broke codegen on all dispatches (+386 us) — keep the
// body flat. R8 TRIPWIRE: atomicAdd-based stats are nondeterministic and
// the variance formula's cancellation amplifies ordering noise past the
// accuracy threshold on some calls — stats partials must be written to
// per-block slots and reduced in fixed order. NO atomics into variance.
__global__ __launch_bounds__(256, 4) void gemm_bt(
    const BF* __restrict__ A, const BF* __restrict__ W, const float* __restrict__ bias,
    BF* __restrict__ outB, float* __restrict__ outF, BF* __restrict__ outV,
    float* __restrict__ hpart,
    int M, int N, int K, int nbx,
    long long strideA, long long strideW, long long strideC,
    float scale, int flags)
{
  const int id = blockIdx.x;
  int z, bx, by;
  if (flags & GF_BATCH8) {
    z = id & 7;
    const int t = id >> 3;
    bx = t % nbx;
    by = t / nbx;
    if (flags & GF_KCAP) by = (M >> 7) - 1 - by;  // long-K tiles first
  } else {
    z = 0;
    by = (id & 7) + ((id >> 3) & 15) * 8;  // m-panel, XCD-pinned (128 panels)
    bx = id >> 7;
  }
  const int m0 = by * 128;
  const int n0 = bx * 128;
  if ((flags & GF_CAUSAL) && n0 > m0) return;  // tile fully above diagonal

  const BF* __restrict__ Ab = A + (size_t)z * strideA;
  const BF* __restrict__ Wb = W + (size_t)z * strideW;
  const size_t coff = (size_t)z * strideC;

  const int tid = threadIdx.x;
  const int w = tid >> 6;
  const int lane = tid & 63;
  const int lane15 = lane & 15;
  const int quad = lane >> 4;
  const int wr = w >> 1, wc = w & 1;
  const int rl = lane >> 2;
  const int clsw = ((lane & 3) ^ ((rl >> 1) & 3)) << 3;  // swizzled k-offset in elements

  // 32 KB merged: K-loop view sA/sW dbuf; epilogue view: bf16 tile OR stats scratch.
  __shared__ __align__(16) BF smem[16384];
  BF* sA = smem;
  BF* sW = smem + 8192;

  v4f acc[4][4];
  {
    v4f zero = {0.f, 0.f, 0.f, 0.f};
#pragma unroll
    for (int a = 0; a < 4; ++a)
#pragma unroll
      for (int b = 0; b < 4; ++b) acc[a][b] = zero;
  }

  int Klim = K;
  if (flags & GF_KCAP) { int kc = m0 + 128; if (kc < Klim) Klim = kc; }
  const int ksteps = Klim >> 5;

  auto stage = [&](int kk, int buf) {
    const int k0 = kk << 5;
#pragma unroll
    for (int i = 0; i < 2; ++i) {
      const int r0 = w * 32 + i * 16;  // wave-uniform 16-row chunk
      async16(&sA[buf * 4096 + r0 * 32], Ab + (size_t)(m0 + r0 + rl) * K + (k0 + clsw));
      async16(&sW[buf * 4096 + r0 * 32], Wb + (size_t)(n0 + r0 + rl) * K + (k0 + clsw));
    }
  };

  stage(0, 0);
  const int sw = quad ^ ((lane15 >> 1) & 3);  // read-side swizzle

  for (int kk = 0; kk < ksteps; ++kk) {
    const int cur = kk & 1;
    if (kk + 1 < ksteps) {
      stage(kk + 1, cur ^ 1);                 // prefetch stays in flight across the barrier
      __builtin_amdgcn_s_waitcnt(WAIT_VM4);   // retire only this iter's 4 loads
    } else {
      __builtin_amdgcn_s_waitcnt(WAIT_VM0);
    }
    __builtin_amdgcn_s_barrier();             // buf[cur] fully populated by all waves

    v8bf aF[4], wF[4];
    const v8bf* sAv = (const v8bf*)(sA + cur * 4096);
    const v8bf* sWv = (const v8bf*)(sW + cur * 4096);
#pragma unroll
    for (int t = 0; t < 4; ++t) {
      aF[t] = sAv[(wr * 64 + t * 16 + lane15) * 4 + sw];
      wF[t] = sWv[(wc * 64 + t * 16 + lane15) * 4 + sw];
    }
#pragma unroll
    for (int mt = 0; mt < 4; ++mt)
#pragma unroll
      for (int nt = 0; nt < 4; ++nt)
        acc[mt][nt] = __builtin_amdgcn_mfma_f32_16x16x32_bf16(aF[mt], wF[nt], acc[mt][nt], 0, 0, 0);
    __builtin_amdgcn_s_barrier();             // all waves consumed buf[cur]
  }

  // ---- epilogue ----
  // C/D layout col=lane&15, row=quad*4+i
  if ((flags & GF_QKV) || (outB && !outF)) {
    // bf16 path: stage tile in LDS (chunk-XOR swizzle), then 8 coalesced
    // 16B stores per thread.
#pragma unroll
    for (int mt = 0; mt < 4; ++mt) {
#pragma unroll
      for (int nt = 0; nt < 4; ++nt) {
        const int col = wc * 64 + nt * 16 + lane15;
        const int cg = n0 + col;
        const float bv = bias ? bias[cg] : 0.0f;
#pragma unroll
        for (int i = 0; i < 4; ++i) {
          const int row = wr * 64 + mt * 16 + quad * 4 + i;
          float v = acc[mt][nt][i] * scale + bv;
          if ((flags & GF_RELU) && v < 0.f) v = 0.f;
          if ((flags & GF_CAUSAL) && cg > m0 + row) v = 0.f;
          smem[row * 128 + ((((col >> 3) ^ ((row >> 2) & 3)) << 3) | (col & 7))] =
              __float2bfloat16(v);
        }
      }
    }
    __syncthreads();
    BF* dst;
    int ldc, coloff;
    if (flags & GF_QKV) {
      const int seg = n0 >> 9;  // 128-col tile lies wholly in q, k, or v
      dst = (seg == 0) ? outB : (seg == 1 ? (BF*)outF : outV);
      ldc = 512;
      coloff = n0 & 511;
    } else {
      dst = outB + coff;
      ldc = N;
      coloff = n0;
    }
#pragma unroll
    for (int p = 0; p < 8; ++p) {
      const int g = p * 256 + tid;
      const int row = g >> 4, ch = g & 15;
      const v8bf val = *(const v8bf*)(smem + row * 128 + ((ch ^ ((row >> 2) & 3)) << 3));
      *(v8bf*)(dst + (size_t)(m0 + row) * ldc + coloff + ch * 8) = val;
    }
  } else {
    // fp32 path (h32): scalar stores + optional fused column stats
    float psum[4] = {0.f, 0.f, 0.f, 0.f};
    float psq[4] = {0.f, 0.f, 0.f, 0.f};
#pragma unroll
    for (int mt = 0; mt < 4; ++mt) {
      const int rb = m0 + wr * 64 + mt * 16 + quad * 4;
#pragma unroll
      for (int nt = 0; nt < 4; ++nt) {
        const int cg = n0 + wc * 64 + nt * 16 + lane15;
        const float bv = bias ? bias[cg] : 0.0f;
#pragma unroll
        for (int i = 0; i < 4; ++i) {
          const int rg = rb + i;
          float v = acc[mt][nt][i] * scale + bv;
          if ((flags & GF_RELU) && v < 0.f) v = 0.f;
          if ((flags & GF_CAUSAL) && cg > rg) v = 0.f;
          if (outB) outB[coff + (size_t)rg * N + cg] = __float2bfloat16(v);
          if (outF) outF[coff + (size_t)rg * N + cg] = v;
          psum[nt] += v;
          psq[nt] += v * v;
        }
      }
    }
    if (flags & GF_HSTAT) {
      // deterministic per-block partials: each (z,bx,by) block owns slot
      // hpart[((z*4+bx)*16+by)*256 + {0..127 sum | 128..255 sq}].
      // No atomics — R8 tripwire lesson.
      float* fs = (float*)smem;
      __syncthreads();  // K-loop reads of smem are done
#pragma unroll
      for (int nt = 0; nt < 4; ++nt) {
        const int col = wc * 64 + nt * 16 + lane15;
        const int cont = wr * 4 + quad;
        fs[col * 8 + cont] = psum[nt];
        fs[1024 + col * 8 + cont] = psq[nt];
      }
      __syncthreads();
      if (tid < 128) {
        float s = 0.f, q = 0.f;
#pragma unroll
        for (int c = 0; c < 8; ++c) { s += fs[tid * 8 + c]; q += fs[1024 + tid * 8 + c]; }
        float* hp = hpart + ((size_t)((z * 4 + bx) * 16 + by)) * 256;
        hp[tid] = s;
        hp[128 + tid] = q;
      }
    }
  }
}

// x[b,s,:] = concat(emb_table[idx[b,s]][0:448], feats[b,s,0:64]) -> bf16
__global__ void gather_kernel(const int* __restrict__ seq, const float* __restrict__ feats,
                              const float* __restrict__ emb, BF* __restrict__ xb) {
  const int row = blockIdx.x;  // b*SEQ + s
  const int t = threadIdx.x;
  const int idx = seq[row];
  BF* xr = xb + (size_t)row * DIMC;
  if (t < 224) {
    const float2 e = *(const float2*)(emb + (size_t)idx * 448 + t * 2);
    xr[t * 2] = __float2bfloat16(e.x);
    xr[t * 2 + 1] = __float2bfloat16(e.y);
  } else {
    const int j = (t - 224) * 2;
    const float2 f = *(const float2*)(feats + (size_t)row * 64 + j);
    xr[448 + j] = __float2bfloat16(f.x);
    xr[448 + j + 1] = __float2bfloat16(f.y);
  }
}

// one-shot weight prep: wb = bf16(W1|W2), wqkv = bf16 packed [2][1536][512],
// bqkv packed bias. (No zeroing needed — stats partials are fully
// overwritten every call.)
__global__ void prep_kernel(const float* __restrict__ W1, const float* __restrict__ W2,
                            const float* __restrict__ Wq, const float* __restrict__ Wk,
                            const float* __restrict__ Wv, const float* __restrict__ bq,
                            const float* __restrict__ bk, const float* __restrict__ bv,
                            BF* __restrict__ wb, BF* __restrict__ wqkv, float* __restrict__ bqkv) {
  const int t = blockIdx.x * 256 + threadIdx.x;  // 655,360 threads
  const long long i = (long long)t * 4;
  float4 v;
  BF* o;
  if (i < 1048576) {  // wb: W1 | W2 (each 524,288)
    v = (i < 524288) ? *(const float4*)(W1 + i) : *(const float4*)(W2 + (i - 524288));
    o = wb + i;
  } else {            // wqkv: [l][q|k|v row][col]
    const long long j = i - 1048576;
    const int l = j >= 786432 ? 1 : 0;
    const long long rem = j - (long long)l * 786432;
    const int r = (int)(rem >> 9), c = (int)(rem & 511);
    const float* s = (r < 512) ? Wq : (r < 1024 ? Wk : Wv);
    v = *(const float4*)(s + (size_t)l * 262144 + (size_t)(r & 511) * 512 + c);
    o = wqkv + j;
  }
  o[0] = __float2bfloat16(v.x); o[1] = __float2bfloat16(v.y);
  o[2] = __float2bfloat16(v.z); o[3] = __float2bfloat16(v.w);
  if (t < 768) {  // bqkv: 3072 elems
#pragma unroll
    for (int e = t * 4; e < t * 4 + 4; ++e) {
      const int l = e / 1536, r = e % 1536;
      const float* s = (r < 512) ? bq : (r < 1024 ? bk : bv);
      bqkv[e] = s[l * 512 + (r & 511)];
    }
  }
}

// vtmp [b][s][512] bf16 -> vt [b][512][s] bf16, 64x64 LDS tiles
__global__ void transpose_kernel(const BF* __restrict__ in, BF* __restrict__ out) {
  __shared__ BF t[64][65];
  const int b = blockIdx.z;
  const int s0 = blockIdx.x * 64, d0 = blockIdx.y * 64;
  const int dx = threadIdx.x & 63, ry = threadIdx.x >> 6;  // ry in 0..3
  const BF* ib = in + ((size_t)b * SEQ + s0) * DIMC + d0;
  BF* ob = out + ((size_t)b * DIMC + d0) * SEQ + s0;
#pragma unroll
  for (int i = 0; i < 16; ++i)
    t[ry + i * 4][dx] = ib[(size_t)(ry + i * 4) * DIMC + dx];
  __syncthreads();
#pragma unroll
  for (int i = 0; i < 16; ++i)
    ob[(size_t)(ry + i * 4) * SEQ + dx] = t[dx][ry + i * 4];
}

// stats from deterministic partials: fixed-order 16-way reduction per (b,d)
__global__ void seqstat_kernel(const float* __restrict__ hpart, float2* __restrict__ stat) {
  const int i = blockIdx.x * 256 + threadIdx.x;  // 4096 = 8*512
  const int b = i >> 9, d = i & 511;
  const int bx = d >> 7, col = d & 127;
  const float* hp = hpart + ((size_t)(b * 4 + bx) * 16) * 256 + col;
  float s = 0.f, q = 0.f;
#pragma unroll
  for (int by = 0; by < 16; ++by) {  // fixed order -> bit-deterministic
    s += hp[by * 256];
    q += hp[by * 256 + 128];
  }
  const float mean = s / SEQ;
  float var = (q - mean * s) / (SEQ - 1);
  if (var < 0.f) var = 0.f;
  stat[i] = make_float2(mean, 1.0f / (sqrtf(var) + 2e-5f));
}

__global__ void seqapply_kernel(const float* __restrict__ h, const float2* __restrict__ stat,
                                BF* __restrict__ out) {
  const size_t i = ((size_t)blockIdx.x * 256 + threadIdx.x) * 4;  // 16,777,216 elems
  const int b = (int)(i >> 20);                                   // SEQ*DIMC = 2^20
  const int d = (int)(i & 511);
  const float4 v = *(const float4*)(h + i);
  const float2* sb = stat + (b << 9) + d;
  const float4 s01 = *(const float4*)(sb);
  const float4 s23 = *(const float4*)(sb + 2);
  out[i]     = __float2bfloat16((v.x - s01.x) * s01.y);
  out[i + 1] = __float2bfloat16((v.y - s01.z) * s01.w);
  out[i + 2] = __float2bfloat16((v.z - s23.x) * s23.y);
  out[i + 3] = __float2bfloat16((v.w - s23.z) * s23.w);
}

// R2 tail: last-row-only layer-1 ffn, 64 blocks/kernel.
__global__ void ffn1last_kernel(const float* __restrict__ h32, const float2* __restrict__ stat,
                                const BF* __restrict__ W1B, const float* __restrict__ b1,
                                float* __restrict__ f1g) {
  const int b = blockIdx.x >> 3, nb = blockIdx.x & 7;  // 64 blocks
  const int t = threadIdx.x;
  __shared__ float hn[512];
  const float* hr = h32 + ((size_t)b * SEQ + (SEQ - 1)) * DIMC;
  const float2* sb = stat + b * 512;
  for (int d = t; d < 512; d += 256) {
    const float2 s = sb[d];
    hn[d] = (hr[d] - s.x) * s.y;
  }
  __syncthreads();
  const int o = nb * 64 + (t >> 2);   // output column
  const int seg = t & 3;              // k-segment of 128
  const BF* wr = W1B + (size_t)o * 512 + seg * 128;
  const float* hs = hn + seg * 128;
  float acc = 0.f;
#pragma unroll
  for (int j = 0; j < 128; j += 8) {
    const v8bf wv = *(const v8bf*)(wr + j);
#pragma unroll
    for (int e = 0; e < 8; ++e) acc += hs[j + e] * (float)wv[e];
  }
  acc += __shfl_xor(acc, 1, 64);
  acc += __shfl_xor(acc, 2, 64);
  if (seg == 0) {
    const float v = acc + b1[o];
    f1g[b * 512 + o] = v > 0.f ? v : 0.f;
  }
}

__global__ void ffn2last_kernel(const float* __restrict__ f1g, const BF* __restrict__ W2B,
                                const float* __restrict__ b2, float* __restrict__ out) {
  const int b = blockIdx.x >> 3, nb = blockIdx.x & 7;  // 64 blocks
  const int t = threadIdx.x;
  __shared__ float f1[512];
  const float* fr = f1g + b * 512;
  for (int d = t; d < 512; d += 256) f1[d] = fr[d];
  __syncthreads();
  const int o = nb * 64 + (t >> 2);
  const int seg = t & 3;
  const BF* wr = W2B + (size_t)o * 512 + seg * 128;
  const float* fs = f1 + seg * 128;
  float acc = 0.f;
#pragma unroll
  for (int j = 0; j < 128; j += 8) {
    const v8bf wv = *(const v8bf*)(wr + j);
#pragma unroll
    for (int e = 0; e < 8; ++e) acc += fs[j + e] * (float)wv[e];
  }
  acc += __shfl_xor(acc, 1, 64);
  acc += __shfl_xor(acc, 2, 64);
  if (seg == 0) out[b * 512 + o] = acc + b2[o];
}

extern "C" void kernel_launch(void* const* d_in, const int* in_sizes, int n_in,
                              void* d_out, int out_size, void* d_ws, size_t ws_size,
                              hipStream_t stream) {
  const int* seq = (const int*)d_in[0];
  const float* feats = (const float*)d_in[1];
  const float* emb = (const float*)d_in[2];
  const float* Wq = (const float*)d_in[3];
  const float* bq = (const float*)d_in[4];
  const float* Wk = (const float*)d_in[5];
  const float* bk = (const float*)d_in[6];
  const float* Wv = (const float*)d_in[7];
  const float* bv = (const float*)d_in[8];
  const float* W1 = (const float*)d_in[9];
  const float* b1 = (const float*)d_in[10];
  const float* W2 = (const float*)d_in[11];
  const float* b2 = (const float*)d_in[12];
  float* out = (float*)d_out;

  char* ws = (char*)d_ws;
  const size_t MB = 1024 * 1024;
  BF* xb = (BF*)(ws);                   // 16 MB: x bf16 (also x_next)
  BF* qb = (BF*)(ws + 16 * MB);         // 16 MB: q bf16 (also hn l0)
  BF* kb = (BF*)(ws + 32 * MB);         // 16 MB: k bf16 (also f1 l0)
  BF* vt = (BF*)(ws + 48 * MB);         // 16 MB: v^T bf16 [b][d][s]
  float* h32 = (float*)(ws + 64 * MB);  // 32 MB: attention out fp32
  BF* vtmp = (BF*)(ws + 64 * MB);       // overlays h32 head: v [b][s][d] before transpose
  BF* sc = (BF*)(ws + 96 * MB);         // 64 MB: scores bf16 [b][s][n]
  BF* wb = (BF*)(ws + 160 * MB);        // 2 MB: bf16 W1,W2
  BF* wqkv = (BF*)(ws + 162 * MB);      // 3 MB: bf16 packed qkv weights [2][1536][512]
  float* bqkv = (float*)(ws + 166 * MB);// 12 KB: packed qkv bias [2][1536]
  float* f1g = (float*)(ws + 166 * MB + 512 * 1024);  // 16 KB: last-row f1 fp32 [8][512]
  float* hpart = (float*)(ws + 167 * MB);// 512 KB: stats partials [8][4][16][2][128]
  float2* stat = (float2*)(ws + 168 * MB); // 32 KB: seqnorm mean/rstd [8][512]

  const int WT = 2 * 512 * 512;
  prep_kernel<<<2560, 256, 0, stream>>>(W1, W2, Wq, Wk, Wv, bq, bk, bv, wb, wqkv, bqkv);
  gather_kernel<<<BSZ * SEQ, 256, 0, stream>>>(seq, feats, emb, xb);

  const float attn_scale = 0.04419417382415922f;  // 1/sqrt(512)
  const dim3 blk(256);

  for (int l = 0; l < 2; ++l) {
    const BF* W1B = wb + (size_t)l * 262144;
    const BF* W2B = wb + (size_t)WT + (size_t)l * 262144;

    // fused q|k|v projection: M=16384, N=1536, K=512 (1536 blocks, XCD-pinned m-panels)
    gemm_bt<<<1536, blk, 0, stream>>>(xb, wqkv + (size_t)l * 786432, bqkv + l * 1536,
        qb, (float*)kb, vtmp, nullptr,
        16384, 1536, 512, 12, 0, 0, 0, 1.0f, GF_QKV);
    // coalesced v transpose -> vt [b][d][s]
    transpose_kernel<<<dim3(32, 8, 8), blk, 0, stream>>>(vtmp, vt);
    // scores = tril(q @ k^T) * scale (batch = id&7, XCD-pinned)
    gemm_bt<<<2048, blk, 0, stream>>>(qb, kb, nullptr, sc, nullptr, nullptr,
        nullptr, 2048, 2048, 512, 16,
        (long long)SEQ * DIMC, (long long)SEQ * DIMC, (long long)SEQ * SEQ,
        attn_scale, GF_CAUSAL | GF_BATCH8);
    // h = scores @ v (batch = id&7, K capped; long-K first) + deterministic stats
    gemm_bt<<<512, blk, 0, stream>>>(sc, vt, nullptr, nullptr, h32, nullptr,
        hpart, 2048, 512, 2048, 4,
        (long long)SEQ * SEQ, (long long)DIMC * SEQ, (long long)SEQ * DIMC,
        1.0f, GF_KCAP | GF_BATCH8 | GF_HSTAT);
    // stats -> mean/rstd (fixed-order reduction, bit-deterministic)
    seqstat_kernel<<<16, 256, 0, stream>>>(hpart, stat);

    if (l == 0) {
      // full normalize + ffn (layer-0 output feeds layer-1 attention)
      seqapply_kernel<<<16384, 256, 0, stream>>>(h32, stat, qb);
      gemm_bt<<<512, blk, 0, stream>>>(qb, W1B, b1 + l * 512, kb, nullptr, nullptr,
          nullptr, 16384, 512, 512, 4, 0, 0, 0, 1.0f, GF_RELU);
      gemm_bt<<<512, blk, 0, stream>>>(kb, W2B, b2 + l * 512, xb,
          nullptr, nullptr, nullptr, 16384, 512, 512, 4, 0, 0, 0, 1.0f, 0);
    } else {
      // layer-1: only the last row survives to the output — parallel fused tail
      ffn1last_kernel<<<64, blk, 0, stream>>>(h32, stat, W1B, b1 + 512, f1g);
      ffn2last_kernel<<<64, blk, 0, stream>>>(f1g, W2B, b2 + 512, out);
    }
  }
}

// Round 11
// 428.977 us; speedup vs baseline: 1.9346x; 1.0082x over previous
//
#include <hip/hip_runtime.h>
#include <hip/hip_bf16.h>

typedef __hip_bfloat16 BF;
typedef __bf16 v8bf __attribute__((ext_vector_type(8)));
typedef float v4f __attribute__((ext_vector_type(4)));

constexpr int SEQ = 2048;
constexpr int DIMC = 512;
constexpr int BSZ = 8;

// flags
#define GF_RELU 1
#define GF_CAUSAL 2   // mask col>row with 0, skip tiles entirely above diagonal
#define GF_KCAP 4     // limit K-loop to diagonal cap (h GEMM); also reverses by-order
#define GF_QKV 8      // route columns: 0-511->outB(q), 512-1023->outF-as-BF(k), 1024-1535->outV(v)
#define GF_BATCH8 16  // 1D grid, batch z = id&7 (XCD-pinned batches)
#define GF_HSTAT 32   // fp32 epilogue also writes per-block column sum/sumsq partials

// s_waitcnt immediates (gfx9: vmcnt[3:0]+[15:14], expcnt[6:4]=7 nowait, lgkmcnt[11:8]=0xF nowait)
#define WAIT_VM4 0x0F74
#define WAIT_VM0 0x0F70

__device__ __forceinline__ void async16(BF* lds, const BF* g) {
  __builtin_amdgcn_global_load_lds(
      (const __attribute__((address_space(1))) void*)g,
      (__attribute__((address_space(3))) void*)lds,
      16, 0, 0);
}

// C[M,N] = A[M,K] @ W[N,K]^T (both K-contiguous), bf16 in, fp32 accum.
// Proven structure: 128x128 tile, BK=32, dbuf LDS 32 KB, prefetch dist-1,
// vmcnt(4)-gated barriers, XOR swizzle, 4 blocks/CU.
// Ledger: R1 256^2/8-phase regressed (grid tails, shallow K). R4 256x128 at
// 6 waves/EU SPILLED (unified VGPR; max 4 waves/EU; slots pinned at 1024).
// R4 LDS-coalesced bf16 stores: -77 us. R7 GF_PAIR rp-loop: broke codegen
// on all dispatches (+386 us) — keep the body flat. R8/R10 TRIPWIRE
// (intermittent replay divergence): raw s_barrier after the K-loop has NO
// fence semantics — hipcc may sink ds_reads/MFMAs past it, racing with the
// epilogue's smem writes from other waves. FIX: __syncthreads() (waitcnt +
// fence + barrier) before ANY epilogue smem write. Also: no atomics into
// variance (cancellation amplifies ordering noise — R8). R10: v^T direct
// store from qkv epilogue measured NET-NEGATIVE (-3 us: scatter stores cost
// more than the dedicated transpose kernel) — reverted, keep transpose.
__global__ __launch_bounds__(256, 4) void gemm_bt(
    const BF* __restrict__ A, const BF* __restrict__ W, const float* __restrict__ bias,
    BF* __restrict__ outB, float* __restrict__ outF, BF* __restrict__ outV,
    float* __restrict__ hpart,
    int M, int N, int K, int nbx,
    long long strideA, long long strideW, long long strideC,
    float scale, int flags)
{
  const int id = blockIdx.x;
  int z, bx, by;
  if (flags & GF_BATCH8) {
    z = id & 7;
    const int t = id >> 3;
    bx = t % nbx;
    by = t / nbx;
    if (flags & GF_KCAP) by = (M >> 7) - 1 - by;  // long-K tiles first
  } else {
    z = 0;
    by = (id & 7) + ((id >> 3) & 15) * 8;  // m-panel, XCD-pinned (128 panels)
    bx = id >> 7;
  }
  const int m0 = by * 128;
  const int n0 = bx * 128;
  if ((flags & GF_CAUSAL) && n0 > m0) return;  // tile fully above diagonal

  const BF* __restrict__ Ab = A + (size_t)z * strideA;
  const BF* __restrict__ Wb = W + (size_t)z * strideW;
  const size_t coff = (size_t)z * strideC;

  const int tid = threadIdx.x;
  const int w = tid >> 6;
  const int lane = tid & 63;
  const int lane15 = lane & 15;
  const int quad = lane >> 4;
  const int wr = w >> 1, wc = w & 1;
  const int rl = lane >> 2;
  const int clsw = ((lane & 3) ^ ((rl >> 1) & 3)) << 3;  // swizzled k-offset in elements

  // 32 KB merged: K-loop view sA/sW dbuf; epilogue view: bf16 tile OR stats scratch.
  __shared__ __align__(16) BF smem[16384];
  BF* sA = smem;
  BF* sW = smem + 8192;

  v4f acc[4][4];
  {
    v4f zero = {0.f, 0.f, 0.f, 0.f};
#pragma unroll
    for (int a = 0; a < 4; ++a)
#pragma unroll
      for (int b = 0; b < 4; ++b) acc[a][b] = zero;
  }

  int Klim = K;
  if (flags & GF_KCAP) { int kc = m0 + 128; if (kc < Klim) Klim = kc; }
  const int ksteps = Klim >> 5;

  auto stage = [&](int kk, int buf) {
    const int k0 = kk << 5;
#pragma unroll
    for (int i = 0; i < 2; ++i) {
      const int r0 = w * 32 + i * 16;  // wave-uniform 16-row chunk
      async16(&sA[buf * 4096 + r0 * 32], Ab + (size_t)(m0 + r0 + rl) * K + (k0 + clsw));
      async16(&sW[buf * 4096 + r0 * 32], Wb + (size_t)(n0 + r0 + rl) * K + (k0 + clsw));
    }
  };

  stage(0, 0);
  const int sw = quad ^ ((lane15 >> 1) & 3);  // read-side swizzle

  for (int kk = 0; kk < ksteps; ++kk) {
    const int cur = kk & 1;
    if (kk + 1 < ksteps) {
      stage(kk + 1, cur ^ 1);                 // prefetch stays in flight across the barrier
      __builtin_amdgcn_s_waitcnt(WAIT_VM4);   // retire only this iter's 4 loads
    } else {
      __builtin_amdgcn_s_waitcnt(WAIT_VM0);
    }
    __builtin_amdgcn_s_barrier();             // buf[cur] fully populated by all waves

    v8bf aF[4], wF[4];
    const v8bf* sAv = (const v8bf*)(sA + cur * 4096);
    const v8bf* sWv = (const v8bf*)(sW + cur * 4096);
#pragma unroll
    for (int t = 0; t < 4; ++t) {
      aF[t] = sAv[(wr * 64 + t * 16 + lane15) * 4 + sw];
      wF[t] = sWv[(wc * 64 + t * 16 + lane15) * 4 + sw];
    }
#pragma unroll
    for (int mt = 0; mt < 4; ++mt)
#pragma unroll
      for (int nt = 0; nt < 4; ++nt)
        acc[mt][nt] = __builtin_amdgcn_mfma_f32_16x16x32_bf16(aF[mt], wF[nt], acc[mt][nt], 0, 0, 0);
    __builtin_amdgcn_s_barrier();             // all waves consumed buf[cur]
  }

  // ---- epilogue ----
  // C/D layout col=lane&15, row=quad*4+i
  if ((flags & GF_QKV) || (outB && !outF)) {
    // R11 fence: raw s_barrier above has no memory-fence semantics; this
    // __syncthreads() guarantees no wave still has K-loop LDS reads in
    // flight (or sunk past the barrier) before we overwrite smem.
    __syncthreads();
    // bf16 path: stage tile in LDS (chunk-XOR swizzle), then 8 coalesced
    // 16B stores per thread.
#pragma unroll
    for (int mt = 0; mt < 4; ++mt) {
#pragma unroll
      for (int nt = 0; nt < 4; ++nt) {
        const int col = wc * 64 + nt * 16 + lane15;
        const int cg = n0 + col;
        const float bv = bias ? bias[cg] : 0.0f;
#pragma unroll
        for (int i = 0; i < 4; ++i) {
          const int row = wr * 64 + mt * 16 + quad * 4 + i;
          float v = acc[mt][nt][i] * scale + bv;
          if ((flags & GF_RELU) && v < 0.f) v = 0.f;
          if ((flags & GF_CAUSAL) && cg > m0 + row) v = 0.f;
          smem[row * 128 + ((((col >> 3) ^ ((row >> 2) & 3)) << 3) | (col & 7))] =
              __float2bfloat16(v);
        }
      }
    }
    __syncthreads();
    BF* dst;
    int ldc, coloff;
    if (flags & GF_QKV) {
      const int seg = n0 >> 9;  // 128-col tile lies wholly in q, k, or v
      dst = (seg == 0) ? outB : (seg == 1 ? (BF*)outF : outV);
      ldc = 512;
      coloff = n0 & 511;
    } else {
      dst = outB + coff;
      ldc = N;
      coloff = n0;
    }
#pragma unroll
    for (int p = 0; p < 8; ++p) {
      const int g = p * 256 + tid;
      const int row = g >> 4, ch = g & 15;
      const v8bf val = *(const v8bf*)(smem + row * 128 + ((ch ^ ((row >> 2) & 3)) << 3));
      *(v8bf*)(dst + (size_t)(m0 + row) * ldc + coloff + ch * 8) = val;
    }
  } else {
    // fp32 path (h32): scalar stores + optional fused column stats
    float psum[4] = {0.f, 0.f, 0.f, 0.f};
    float psq[4] = {0.f, 0.f, 0.f, 0.f};
#pragma unroll
    for (int mt = 0; mt < 4; ++mt) {
      const int rb = m0 + wr * 64 + mt * 16 + quad * 4;
#pragma unroll
      for (int nt = 0; nt < 4; ++nt) {
        const int cg = n0 + wc * 64 + nt * 16 + lane15;
        const float bv = bias ? bias[cg] : 0.0f;
#pragma unroll
        for (int i = 0; i < 4; ++i) {
          const int rg = rb + i;
          float v = acc[mt][nt][i] * scale + bv;
          if ((flags & GF_RELU) && v < 0.f) v = 0.f;
          if ((flags & GF_CAUSAL) && cg > rg) v = 0.f;
          if (outB) outB[coff + (size_t)rg * N + cg] = __float2bfloat16(v);
          if (outF) outF[coff + (size_t)rg * N + cg] = v;
          psum[nt] += v;
          psq[nt] += v * v;
        }
      }
    }
    if (flags & GF_HSTAT) {
      // deterministic per-block partials: each (z,bx,by) block owns slot
      // hpart[((z*4+bx)*16+by)*256 + {0..127 sum | 128..255 sq}].
      // No atomics — R8 lesson. __syncthreads = fence before smem reuse.
      float* fs = (float*)smem;
      __syncthreads();
#pragma unroll
      for (int nt = 0; nt < 4; ++nt) {
        const int col = wc * 64 + nt * 16 + lane15;
        const int cont = wr * 4 + quad;
        fs[col * 8 + cont] = psum[nt];
        fs[1024 + col * 8 + cont] = psq[nt];
      }
      __syncthreads();
      if (tid < 128) {
        float s = 0.f, q = 0.f;
#pragma unroll
        for (int c = 0; c < 8; ++c) { s += fs[tid * 8 + c]; q += fs[1024 + tid * 8 + c]; }
        float* hp = hpart + ((size_t)((z * 4 + bx) * 16 + by)) * 256;
        hp[tid] = s;
        hp[128 + tid] = q;
      }
    }
  }
}

// x[b,s,:] = concat(emb_table[idx[b,s]][0:448], feats[b,s,0:64]) -> bf16
__global__ void gather_kernel(const int* __restrict__ seq, const float* __restrict__ feats,
                              const float* __restrict__ emb, BF* __restrict__ xb) {
  const int row = blockIdx.x;  // b*SEQ + s
  const int t = threadIdx.x;
  const int idx = seq[row];
  BF* xr = xb + (size_t)row * DIMC;
  if (t < 224) {
    const float2 e = *(const float2*)(emb + (size_t)idx * 448 + t * 2);
    xr[t * 2] = __float2bfloat16(e.x);
    xr[t * 2 + 1] = __float2bfloat16(e.y);
  } else {
    const int j = (t - 224) * 2;
    const float2 f = *(const float2*)(feats + (size_t)row * 64 + j);
    xr[448 + j] = __float2bfloat16(f.x);
    xr[448 + j + 1] = __float2bfloat16(f.y);
  }
}

// one-shot weight prep: wb = bf16(W1|W2), wqkv = bf16 packed [2][1536][512],
// bqkv packed bias.
__global__ void prep_kernel(const float* __restrict__ W1, const float* __restrict__ W2,
                            const float* __restrict__ Wq, const float* __restrict__ Wk,
                            const float* __restrict__ Wv, const float* __restrict__ bq,
                            const float* __restrict__ bk, const float* __restrict__ bv,
                            BF* __restrict__ wb, BF* __restrict__ wqkv, float* __restrict__ bqkv) {
  const int t = blockIdx.x * 256 + threadIdx.x;  // 655,360 threads
  const long long i = (long long)t * 4;
  float4 v;
  BF* o;
  if (i < 1048576) {  // wb: W1 | W2 (each 524,288)
    v = (i < 524288) ? *(const float4*)(W1 + i) : *(const float4*)(W2 + (i - 524288));
    o = wb + i;
  } else {            // wqkv: [l][q|k|v row][col]
    const long long j = i - 1048576;
    const int l = j >= 786432 ? 1 : 0;
    const long long rem = j - (long long)l * 786432;
    const int r = (int)(rem >> 9), c = (int)(rem & 511);
    const float* s = (r < 512) ? Wq : (r < 1024 ? Wk : Wv);
    v = *(const float4*)(s + (size_t)l * 262144 + (size_t)(r & 511) * 512 + c);
    o = wqkv + j;
  }
  o[0] = __float2bfloat16(v.x); o[1] = __float2bfloat16(v.y);
  o[2] = __float2bfloat16(v.z); o[3] = __float2bfloat16(v.w);
  if (t < 768) {  // bqkv: 3072 elems
#pragma unroll
    for (int e = t * 4; e < t * 4 + 4; ++e) {
      const int l = e / 1536, r = e % 1536;
      const float* s = (r < 512) ? bq : (r < 1024 ? bk : bv);
      bqkv[e] = s[l * 512 + (r & 511)];
    }
  }
}

// vtmp [b][s][512] bf16 -> vt [b][512][s] bf16, 64x64 LDS tiles
__global__ void transpose_kernel(const BF* __restrict__ in, BF* __restrict__ out) {
  __shared__ BF t[64][65];
  const int b = blockIdx.z;
  const int s0 = blockIdx.x * 64, d0 = blockIdx.y * 64;
  const int dx = threadIdx.x & 63, ry = threadIdx.x >> 6;  // ry in 0..3
  const BF* ib = in + ((size_t)b * SEQ + s0) * DIMC + d0;
  BF* ob = out + ((size_t)b * DIMC + d0) * SEQ + s0;
#pragma unroll
  for (int i = 0; i < 16; ++i)
    t[ry + i * 4][dx] = ib[(size_t)(ry + i * 4) * DIMC + dx];
  __syncthreads();
#pragma unroll
  for (int i = 0; i < 16; ++i)
    ob[(size_t)(ry + i * 4) * SEQ + dx] = t[dx][ry + i * 4];
}

// stats from deterministic partials: fixed-order 16-way reduction per (b,d)
__global__ void seqstat_kernel(const float* __restrict__ hpart, float2* __restrict__ stat) {
  const int i = blockIdx.x * 256 + threadIdx.x;  // 4096 = 8*512
  const int b = i >> 9, d = i & 511;
  const int bx = d >> 7, col = d & 127;
  const float* hp = hpart + ((size_t)(b * 4 + bx) * 16) * 256 + col;
  float s = 0.f, q = 0.f;
#pragma unroll
  for (int by = 0; by < 16; ++by) {  // fixed order -> bit-deterministic
    s += hp[by * 256];
    q += hp[by * 256 + 128];
  }
  const float mean = s / SEQ;
  float var = (q - mean * s) / (SEQ - 1);
  if (var < 0.f) var = 0.f;
  stat[i] = make_float2(mean, 1.0f / (sqrtf(var) + 2e-5f));
}

// R11: grid 8192 (was 16384 = 2x overrun reading poison past h32/stat and
// scribbling kb). 8192*256*4 = 8,388,608 = exactly B*S*D.
__global__ void seqapply_kernel(const float* __restrict__ h, const float2* __restrict__ stat,
                                BF* __restrict__ out) {
  const size_t i = ((size_t)blockIdx.x * 256 + threadIdx.x) * 4;  // 8,388,608 elems
  const int b = (int)(i >> 20);                                   // SEQ*DIMC = 2^20
  const int d = (int)(i & 511);
  const float4 v = *(const float4*)(h + i);
  const float2* sb = stat + (b << 9) + d;
  const float4 s01 = *(const float4*)(sb);
  const float4 s23 = *(const float4*)(sb + 2);
  out[i]     = __float2bfloat16((v.x - s01.x) * s01.y);
  out[i + 1] = __float2bfloat16((v.y - s01.z) * s01.w);
  out[i + 2] = __float2bfloat16((v.z - s23.x) * s23.y);
  out[i + 3] = __float2bfloat16((v.w - s23.z) * s23.w);
}

// R2 tail: last-row-only layer-1 ffn, 64 blocks/kernel.
__global__ void ffn1last_kernel(const float* __restrict__ h32, const float2* __restrict__ stat,
                                const BF* __restrict__ W1B, const float* __restrict__ b1,
                                float* __restrict__ f1g) {
  const int b = blockIdx.x >> 3, nb = blockIdx.x & 7;  // 64 blocks
  const int t = threadIdx.x;
  __shared__ float hn[512];
  const float* hr = h32 + ((size_t)b * SEQ + (SEQ - 1)) * DIMC;
  const float2* sb = stat + b * 512;
  for (int d = t; d < 512; d += 256) {
    const float2 s = sb[d];
    hn[d] = (hr[d] - s.x) * s.y;
  }
  __syncthreads();
  const int o = nb * 64 + (t >> 2);   // output column
  const int seg = t & 3;              // k-segment of 128
  const BF* wr = W1B + (size_t)o * 512 + seg * 128;
  const float* hs = hn + seg * 128;
  float acc = 0.f;
#pragma unroll
  for (int j = 0; j < 128; j += 8) {
    const v8bf wv = *(const v8bf*)(wr + j);
#pragma unroll
    for (int e = 0; e < 8; ++e) acc += hs[j + e] * (float)wv[e];
  }
  acc += __shfl_xor(acc, 1, 64);
  acc += __shfl_xor(acc, 2, 64);
  if (seg == 0) {
    const float v = acc + b1[o];
    f1g[b * 512 + o] = v > 0.f ? v : 0.f;
  }
}

__global__ void ffn2last_kernel(const float* __restrict__ f1g, const BF* __restrict__ W2B,
                                const float* __restrict__ b2, float* __restrict__ out) {
  const int b = blockIdx.x >> 3, nb = blockIdx.x & 7;  // 64 blocks
  const int t = threadIdx.x;
  __shared__ float f1[512];
  const float* fr = f1g + b * 512;
  for (int d = t; d < 512; d += 256) f1[d] = fr[d];
  __syncthreads();
  const int o = nb * 64 + (t >> 2);
  const int seg = t & 3;
  const BF* wr = W2B + (size_t)o * 512 + seg * 128;
  const float* fs = f1 + seg * 128;
  float acc = 0.f;
#pragma unroll
  for (int j = 0; j < 128; j += 8) {
    const v8bf wv = *(const v8bf*)(wr + j);
#pragma unroll
    for (int e = 0; e < 8; ++e) acc += fs[j + e] * (float)wv[e];
  }
  acc += __shfl_xor(acc, 1, 64);
  acc += __shfl_xor(acc, 2, 64);
  if (seg == 0) out[b * 512 + o] = acc + b2[o];
}

extern "C" void kernel_launch(void* const* d_in, const int* in_sizes, int n_in,
                              void* d_out, int out_size, void* d_ws, size_t ws_size,
                              hipStream_t stream) {
  const int* seq = (const int*)d_in[0];
  const float* feats = (const float*)d_in[1];
  const float* emb = (const float*)d_in[2];
  const float* Wq = (const float*)d_in[3];
  const float* bq = (const float*)d_in[4];
  const float* Wk = (const float*)d_in[5];
  const float* bk = (const float*)d_in[6];
  const float* Wv = (const float*)d_in[7];
  const float* bv = (const float*)d_in[8];
  const float* W1 = (const float*)d_in[9];
  const float* b1 = (const float*)d_in[10];
  const float* W2 = (const float*)d_in[11];
  const float* b2 = (const float*)d_in[12];
  float* out = (float*)d_out;

  char* ws = (char*)d_ws;
  const size_t MB = 1024 * 1024;
  BF* xb = (BF*)(ws);                   // 16 MB: x bf16 (also x_next)
  BF* qb = (BF*)(ws + 16 * MB);         // 16 MB: q bf16 (also hn l0)
  BF* kb = (BF*)(ws + 32 * MB);         // 16 MB: k bf16 (also f1 l0)
  BF* vt = (BF*)(ws + 48 * MB);         // 16 MB: v^T bf16 [b][d][s]
  float* h32 = (float*)(ws + 64 * MB);  // 32 MB: attention out fp32
  BF* vtmp = (BF*)(ws + 64 * MB);       // overlays h32 head: v [b][s][d] before transpose
  BF* sc = (BF*)(ws + 96 * MB);         // 64 MB: scores bf16 [b][s][n]
  BF* wb = (BF*)(ws + 160 * MB);        // 2 MB: bf16 W1,W2
  BF* wqkv = (BF*)(ws + 162 * MB);      // 3 MB: bf16 packed qkv weights [2][1536][512]
  float* bqkv = (float*)(ws + 166 * MB);// 12 KB: packed qkv bias [2][1536]
  float* f1g = (float*)(ws + 166 * MB + 512 * 1024);  // 16 KB: last-row f1 fp32 [8][512]
  float* hpart = (float*)(ws + 167 * MB);// 512 KB: stats partials [8][4][16][2][128]
  float2* stat = (float2*)(ws + 168 * MB); // 32 KB: seqnorm mean/rstd [8][512]

  const int WT = 2 * 512 * 512;
  prep_kernel<<<2560, 256, 0, stream>>>(W1, W2, Wq, Wk, Wv, bq, bk, bv, wb, wqkv, bqkv);
  gather_kernel<<<BSZ * SEQ, 256, 0, stream>>>(seq, feats, emb, xb);

  const float attn_scale = 0.04419417382415922f;  // 1/sqrt(512)
  const dim3 blk(256);

  for (int l = 0; l < 2; ++l) {
    const BF* W1B = wb + (size_t)l * 262144;
    const BF* W2B = wb + (size_t)WT + (size_t)l * 262144;

    // fused q|k|v projection: M=16384, N=1536, K=512 (1536 blocks, XCD-pinned m-panels)
    gemm_bt<<<1536, blk, 0, stream>>>(xb, wqkv + (size_t)l * 786432, bqkv + l * 1536,
        qb, (float*)kb, vtmp, nullptr,
        16384, 1536, 512, 12, 0, 0, 0, 1.0f, GF_QKV);
    // coalesced v transpose -> vt [b][d][s]
    transpose_kernel<<<dim3(32, 8, 8), blk, 0, stream>>>(vtmp, vt);
    // scores = tril(q @ k^T) * scale (batch = id&7, XCD-pinned)
    gemm_bt<<<2048, blk, 0, stream>>>(qb, kb, nullptr, sc, nullptr, nullptr,
        nullptr, 2048, 2048, 512, 16,
        (long long)SEQ * DIMC, (long long)SEQ * DIMC, (long long)SEQ * SEQ,
        attn_scale, GF_CAUSAL | GF_BATCH8);
    // h = scores @ v (batch = id&7, K capped; long-K first) + deterministic stats
    gemm_bt<<<512, blk, 0, stream>>>(sc, vt, nullptr, nullptr, h32, nullptr,
        hpart, 2048, 512, 2048, 4,
        (long long)SEQ * SEQ, (long long)DIMC * SEQ, (long long)SEQ * DIMC,
        1.0f, GF_KCAP | GF_BATCH8 | GF_HSTAT);
    // stats -> mean/rstd (fixed-order reduction, bit-deterministic)
    seqstat_kernel<<<16, 256, 0, stream>>>(hpart, stat);

    if (l == 0) {
      // full normalize + ffn (layer-0 output feeds layer-1 attention)
      seqapply_kernel<<<8192, 256, 0, stream>>>(h32, stat, qb);
      gemm_bt<<<512, blk, 0, stream>>>(qb, W1B, b1 + l * 512, kb, nullptr, nullptr,
          nullptr, 16384, 512, 512, 4, 0, 0, 0, 1.0f, GF_RELU);
      gemm_bt<<<512, blk, 0, stream>>>(kb, W2B, b2 + l * 512, xb,
          nullptr, nullptr, nullptr, 16384, 512, 512, 4, 0, 0, 0, 1.0f, 0);
    } else {
      // layer-1: only the last row survives to the output — parallel fused tail
      ffn1last_kernel<<<64, blk, 0, stream>>>(h32, stat, W1B, b1 + 512, f1g);
      ffn2last_kernel<<<64, blk, 0, stream>>>(f1g, W2B, b2 + 512, out);
    }
  }
}